// Round 8
// baseline (318.729 us; speedup 1.0000x reference)
//
#include <hip/hip_runtime.h>

#define TOK 8192   // B*S
#define DIM 512    // D
#define NE  32     // experts
#define KTOT (NE * DIM)

#define BM 128
#define BN 128
#define BK 64

typedef float f32x4  __attribute__((ext_vector_type(4)));
typedef float f32x16 __attribute__((ext_vector_type(16)));
typedef short s16x8  __attribute__((ext_vector_type(8)));

typedef const void __attribute__((address_space(1)))* gp1_t;
typedef void __attribute__((address_space(3)))* lp3_t;

__device__ __forceinline__ void gl_lds16(const void* g, void* l) {
    __builtin_amdgcn_global_load_lds((gp1_t)g, (lp3_t)l, 16, 0, 0);
}

// stage one 16KB tile (128 rows x 128B) with 512 threads: 2 rounds of 16B
// rstride = row stride in ushorts (DIM for A, KTOT for B)
__device__ __forceinline__ void stage2(const ushort* g, size_t rstride, char* l) {
    gl_lds16(g,                 l);
    gl_lds16(g + 64 * rstride,  l + 8192);
}

__device__ __forceinline__ ushort f2bf(float f) {
    unsigned u = __builtin_bit_cast(unsigned, f);
    unsigned r = (u + 0x7fffu + ((u >> 16) & 1u)) >> 16;
    return (ushort)r;
}

// ---- fused prep: blocks [0,2048) transpose+convert W; [2048,3072) gates+cvt x
__global__ __launch_bounds__(256) void k_prep(const float* __restrict__ w,
                                              ushort* __restrict__ wt,
                                              const float* __restrict__ x,
                                              const float* __restrict__ gw,
                                              const float* __restrict__ gb,
                                              float* __restrict__ G,
                                              ushort* __restrict__ xb) {
    __shared__ __align__(16) char smem[64 * 65 * 4];
    const int bx = blockIdx.x;
    const int tid = threadIdx.x;
    if (bx < 2048) {
        // ---- Wt[f][e*512+d] = bf16(w[e][d][f]), 64x64 tile ----
        float (*tile)[65] = (float(*)[65])smem;
        const int e = bx >> 6;
        const int f0 = ((bx >> 3) & 7) * 64;
        const int d0 = (bx & 7) * 64;
        const int tx = tid & 63, ty = tid >> 6;  // ty 0..3
        const float* we = w + (size_t)e * DIM * DIM;
#pragma unroll
        for (int i = ty; i < 64; i += 4)
            tile[i][tx] = we[(size_t)(d0 + i) * DIM + f0 + tx];
        __syncthreads();
#pragma unroll
        for (int i = ty; i < 64; i += 4)
            wt[(size_t)(f0 + i) * KTOT + e * DIM + d0 + tx] = f2bf(tile[tx][i]);
    } else {
        // ---- gates (8 tokens/block, shfl softmax) + x -> bf16 ----
        float* xs = (float*)smem;
        const int t0 = (bx - 2048) * 8;
        const float* xBase = x + (size_t)t0 * DIM;
#pragma unroll
        for (int k = 0; k < 4; ++k) {
            int i4 = (k * 256 + tid) * 4;
            float4 v = *(const float4*)(xBase + i4);
            xs[i4 + 0] = v.x; xs[i4 + 1] = v.y; xs[i4 + 2] = v.z; xs[i4 + 3] = v.w;
            ushort4 o;
            o.x = f2bf(v.x); o.y = f2bf(v.y); o.z = f2bf(v.z); o.w = f2bf(v.w);
            *(ushort4*)(xb + (size_t)t0 * DIM + i4) = o;
        }
        __syncthreads();
        const int tok = tid >> 5;   // 0..7
        const int e = tid & 31;
        float l = gb[e];
        const float* xr = xs + tok * DIM;
#pragma unroll 8
        for (int d = 0; d < DIM; ++d)
            l += xr[d] * gw[d * NE + e];
        float mx = l;
#pragma unroll
        for (int m = 16; m >= 1; m >>= 1) mx = fmaxf(mx, __shfl_xor(mx, m));
        float ex = expf(l - mx);
        float s = ex;
#pragma unroll
        for (int m = 16; m >= 1; m >>= 1) s += __shfl_xor(s, m);
        G[(size_t)(t0 + tok) * NE + e] = ex / s;
    }
}

// ------- main GEMM v9: faithful m201 8-phase anatomy (4 phases / 2 K-tiles) -
// Evidence ledger: five 2-barrier variants all 148-155us (matrix-busy time
// invariant ~60us = pipe idle 60%); three single-barrier counted-vmcnt
// attempts all ~189us. The documented escape (m196->m198->m201, +28-41%+29%)
// is the DOUBLE-barrier phase anatomy with 8 waves/block: waves alternate as
// one mem-issue cluster and one MFMA cluster; counted vmcnt only at the two
// K-tile publish points. v9 = exact transplant:
//   512 thr, 8 waves (2M x 4N of 64x32), BM=BN=128, BK=64, z=2 (16 experts),
//   iter = 2 K-tiles, 4 phases each:
//     {ds_read 4-8 b128; 2 glds (1 half-tile of iter i+1); s_barrier;
//      lgkmcnt(0); sched_barrier(0); setprio(1); 4x mfma 32x32x16;
//      setprio(0); [vmcnt(4) at ph2/ph4]; s_barrier}
//   vmcnt derivation: 8 loads in flight (next iter's 4 half-tiles x 2);
//   at each publish point drain oldest 4 (the K-tile about to be read),
//   keep newest 4. vmcnt(0) only at i=63 ph2. Uniform everywhere else.
//   pacc = per-expert 2x f32x16 (seeded at p==0 via MFMA c-in = 0);
//   gate fold once per expert (p==3) after ph4. No unroll, sparse fences.
// LDS: A 4x16KB + B 4x16KB + Gs 8KB = 136KB -> 1 block/CU, 8 waves = 2/SIMD.
// Swizzle/staging map/C-layout identical to the verified v0/v1 kernels.
__global__ __launch_bounds__(512, 2) void k_moe_gemm(const ushort* __restrict__ xb,
                                                     const ushort* __restrict__ wt,
                                                     const float* __restrict__ G,
                                                     float* __restrict__ out0,
                                                     float* __restrict__ out1) {
    __shared__ __align__(16) ushort As[2][2][BM * BK];   // [dbuf][ktile] 4x16KB
    __shared__ __align__(16) ushort Bs[2][2][BN * BK];   // [dbuf][ktile] 4x16KB
    __shared__ float Gs[16][BM];                         // 8 KB

    const int tid = threadIdx.x;
    const int m0 = blockIdx.y * BM;
    const int n0 = blockIdx.x * BN;
    const int e0 = blockIdx.z * 16;
    float* __restrict__ dst = blockIdx.z ? out1 : out0;

    for (int idx = tid; idx < 16 * BM; idx += 512) {
        int e = idx >> 7, r = idx & 127;
        Gs[e][r] = G[(size_t)(m0 + r) * NE + e0 + e];
    }

    const int lane = tid & 63;
    const int wave = tid >> 6;          // 0..7
    const int wm = (wave >> 2) * 64;    // 2 m-groups
    const int wn = (wave & 3) * 32;     // 4 n-groups
    const int l31 = lane & 31;
    const int hi = lane >> 5;           // 0..1
    const int key = l31 & 7;

    // frag read offsets: row*128 + ((2s+hi) ^ (row&7))*16   (row&7 == key)
    int chunkOff[4];
#pragma unroll
    for (int s = 0; s < 4; ++s) chunkOff[s] = ((2 * s + hi) ^ key) * 16;
    const int rowA0 = (wm + l31) * 128;        // mi=0 rows
    const int rowA1 = (wm + 32 + l31) * 128;   // mi=1 rows
    const int rowB  = (wn + l31) * 128;

    // staging map: 512 thr x 16B = 8KB/round = 64 rows of 128B, 2 rounds/tile
    const int srow = tid >> 3;                       // 0..63
    const int scol = ((tid & 7) ^ (srow & 7)) * 8;   // swizzled global column
    const ushort* aBase = xb + (size_t)(m0 + srow) * DIM + scol;
    const ushort* bBase = wt + (size_t)(n0 + srow) * KTOT + (size_t)e0 * DIM + scol;
    const int ldsOff = tid * 16;

    f32x16 zv16;
#pragma unroll
    for (int j = 0; j < 16; ++j) zv16[j] = 0.f;
    f32x16 accA = zv16, accB = zv16;
    f32x16 paccA, paccB;

    // prologue: stage iter 0 completely: T0(A,B) first 4 ops, T1(A,B) next 4.
    stage2(aBase,      DIM,  (char*)As[0][0] + ldsOff);
    stage2(bBase,      KTOT, (char*)Bs[0][0] + ldsOff);
    stage2(aBase + 64, DIM,  (char*)As[0][1] + ldsOff);
    stage2(bBase + 64, KTOT, (char*)Bs[0][1] + ldsOff);
    asm volatile("s_waitcnt vmcnt(4) lgkmcnt(0)" ::: "memory");  // publish T0, keep T1
    __builtin_amdgcn_s_barrier();

    s16x8 areg[4], breg[4];

#pragma unroll 1
    for (int i = 0; i < 64; ++i) {
        const int d  = i & 1;
        const int p  = i & 3;          // iter within expert (expert = 4 iters)
        const int el = i >> 2;         // local expert 0..15
        const int i1 = i + 1;
        const bool st = (i1 < 64);
        const int dn = i1 & 1;
        const ushort* aN = aBase + (i1 & 3) * 128;
        const ushort* bN = bBase + (size_t)(i1 >> 2) * DIM + (i1 & 3) * 128;
        const char* At0 = (const char*)As[d][0];
        const char* At1 = (const char*)As[d][1];
        const char* Bt0 = (const char*)Bs[d][0];
        const char* Bt1 = (const char*)Bs[d][1];

        // ================ phase 1: T0, mi0 ================
#pragma unroll
        for (int s = 0; s < 4; ++s) {
            areg[s] = *(const s16x8*)(At0 + rowA0 + chunkOff[s]);
            breg[s] = *(const s16x8*)(Bt0 + rowB + chunkOff[s]);
        }
        if (st) stage2(aN, DIM, (char*)As[dn][0] + ldsOff);
        __builtin_amdgcn_s_barrier();
        asm volatile("s_waitcnt lgkmcnt(0)" ::: "memory");
        __builtin_amdgcn_sched_barrier(0);
        __builtin_amdgcn_s_setprio(1);
        paccA = __builtin_amdgcn_mfma_f32_32x32x16_bf16(areg[0], breg[0],
                    (p == 0) ? zv16 : paccA, 0, 0, 0);
#pragma unroll
        for (int s = 1; s < 4; ++s)
            paccA = __builtin_amdgcn_mfma_f32_32x32x16_bf16(areg[s], breg[s], paccA, 0, 0, 0);
        __builtin_amdgcn_s_setprio(0);
        __builtin_amdgcn_s_barrier();

        // ================ phase 2: T0, mi1 ================
#pragma unroll
        for (int s = 0; s < 4; ++s)
            areg[s] = *(const s16x8*)(At0 + rowA1 + chunkOff[s]);
        if (st) stage2(bN, KTOT, (char*)Bs[dn][0] + ldsOff);
        __builtin_amdgcn_s_barrier();
        asm volatile("s_waitcnt lgkmcnt(0)" ::: "memory");
        __builtin_amdgcn_sched_barrier(0);
        __builtin_amdgcn_s_setprio(1);
        paccB = __builtin_amdgcn_mfma_f32_32x32x16_bf16(areg[0], breg[0],
                    (p == 0) ? zv16 : paccB, 0, 0, 0);
#pragma unroll
        for (int s = 1; s < 4; ++s)
            paccB = __builtin_amdgcn_mfma_f32_32x32x16_bf16(areg[s], breg[s], paccB, 0, 0, 0);
        __builtin_amdgcn_s_setprio(0);
        if (i == 63) asm volatile("s_waitcnt vmcnt(0)" ::: "memory");
        else         asm volatile("s_waitcnt vmcnt(4)" ::: "memory");
        __builtin_amdgcn_s_barrier();   // publishes T1 of this iter

        // ================ phase 3: T1, mi0 ================
#pragma unroll
        for (int s = 0; s < 4; ++s) {
            areg[s] = *(const s16x8*)(At1 + rowA0 + chunkOff[s]);
            breg[s] = *(const s16x8*)(Bt1 + rowB + chunkOff[s]);
        }
        if (st) stage2(aN + 64, DIM, (char*)As[dn][1] + ldsOff);
        __builtin_amdgcn_s_barrier();
        asm volatile("s_waitcnt lgkmcnt(0)" ::: "memory");
        __builtin_amdgcn_sched_barrier(0);
        __builtin_amdgcn_s_setprio(1);
#pragma unroll
        for (int s = 0; s < 4; ++s)
            paccA = __builtin_amdgcn_mfma_f32_32x32x16_bf16(areg[s], breg[s], paccA, 0, 0, 0);
        __builtin_amdgcn_s_setprio(0);
        __builtin_amdgcn_s_barrier();

        // ================ phase 4: T1, mi1 ================
#pragma unroll
        for (int s = 0; s < 4; ++s)
            areg[s] = *(const s16x8*)(At1 + rowA1 + chunkOff[s]);
        if (st) stage2(bN + 64, KTOT, (char*)Bs[dn][1] + ldsOff);
        __builtin_amdgcn_s_barrier();
        asm volatile("s_waitcnt lgkmcnt(0)" ::: "memory");
        __builtin_amdgcn_sched_barrier(0);
        __builtin_amdgcn_s_setprio(1);
#pragma unroll
        for (int s = 0; s < 4; ++s)
            paccB = __builtin_amdgcn_mfma_f32_32x32x16_bf16(areg[s], breg[s], paccB, 0, 0, 0);
        __builtin_amdgcn_s_setprio(0);
        if (p == 3) {
            // expert complete: fold pacc into acc with per-row gates
#pragma unroll
            for (int gq = 0; gq < 4; ++gq) {
                const f32x4 gA = *(const f32x4*)&Gs[el][wm + 8 * gq + 4 * hi];
                const f32x4 gB = *(const f32x4*)&Gs[el][wm + 32 + 8 * gq + 4 * hi];
#pragma unroll
                for (int j = 0; j < 4; ++j) {
                    accA[4 * gq + j] += gA[j] * paccA[4 * gq + j];
                    accB[4 * gq + j] += gB[j] * paccB[4 * gq + j];
                }
            }
        }
        asm volatile("s_waitcnt vmcnt(4)" ::: "memory");
        __builtin_amdgcn_s_barrier();   // publishes T0 of next iter
    }

    // epilogue: C/D layout col=lane&31, row=(reg&3)+8*(reg>>2)+4*hi
    const int col = n0 + wn + l31;
#pragma unroll
    for (int gq = 0; gq < 4; ++gq) {
        float* pA = dst + (size_t)(m0 + wm + 8 * gq + 4 * hi) * DIM + col;
        float* pB = dst + (size_t)(m0 + wm + 32 + 8 * gq + 4 * hi) * DIM + col;
#pragma unroll
        for (int j = 0; j < 4; ++j) {
            pA[j * DIM] = accA[4 * gq + j];
            pB[j * DIM] = accB[4 * gq + j];
        }
    }
}

// ---- deterministic two-phase sum: out += P (both fully written upstream) ----
__global__ __launch_bounds__(256) void k_reduce(float* __restrict__ out,
                                                const float* __restrict__ P) {
    int i = (blockIdx.x * 256 + threadIdx.x) * 4;
    float4 a = *(const float4*)(out + i);
    float4 b = *(const float4*)(P + i);
    a.x += b.x; a.y += b.y; a.z += b.z; a.w += b.w;
    *(float4*)(out + i) = a;
}

extern "C" void kernel_launch(void* const* d_in, const int* in_sizes, int n_in,
                              void* d_out, int out_size, void* d_ws, size_t ws_size,
                              hipStream_t stream) {
    const float* x  = (const float*)d_in[0];   // [8192][512]
    const float* gw = (const float*)d_in[1];   // [512][32]
    const float* gb = (const float*)d_in[2];   // [32]
    const float* w  = (const float*)d_in[3];   // [32][512][512]
    float* out = (float*)d_out;                // [8192][512] fp32

    char* ws = (char*)d_ws;
    ushort* xb = (ushort*)ws;                            //  0..8 MiB
    ushort* wt = (ushort*)(ws + (8u << 20));             //  8..24 MiB
    float*  G  = (float*)(ws + (24u << 20));             // 24..25 MiB
    float*  P  = (float*)(ws + (25u << 20));             // 25..41 MiB

    k_prep<<<dim3(2048 + TOK / 8), dim3(256), 0, stream>>>(w, wt, x, gw, gb, G, xb);
    k_moe_gemm<<<dim3(DIM / BN, TOK / BM, 2), dim3(512), 0, stream>>>(xb, wt, G, out, P);
    k_reduce<<<dim3(TOK * DIM / 1024), dim3(256), 0, stream>>>(out, P);
}

// Round 9
// 261.779 us; speedup vs baseline: 1.2175x; 1.2175x over previous
//
#include <hip/hip_runtime.h>

#define TOK 8192   // B*S
#define DIM 512    // D
#define NE  32     // experts
#define KTOT (NE * DIM)

#define BM 128
#define BN 128
#define BK 64

typedef float f32x4 __attribute__((ext_vector_type(4)));
typedef short s16x8 __attribute__((ext_vector_type(8)));

typedef const void __attribute__((address_space(1)))* gp1_t;
typedef void __attribute__((address_space(3)))* lp3_t;

__device__ __forceinline__ void gl_lds16(const void* g, void* l) {
    __builtin_amdgcn_global_load_lds((gp1_t)g, (lp3_t)l, 16, 0, 0);
}

__device__ __forceinline__ ushort f2bf(float f) {
    unsigned u = __builtin_bit_cast(unsigned, f);
    unsigned r = (u + 0x7fffu + ((u >> 16) & 1u)) >> 16;
    return (ushort)r;
}

// ---- fused prep v2: blocks [0,2048) transpose+convert W (vectorized);
// ----                [2048,3072) gates+cvt x (byte-identical to proven code)
// Transpose path rewrite (R8 theory: k_prep ~85us = inst/latency-bound,
// scalar 4B loads + scalar 2B stores). Now: float4 gathers -> LDS [d][f]
// (65-pad: store lanes conflict-free, read lanes 2-way=free) -> ushort8
// 16B stores. Output BIT-IDENTICAL (same f2bf), gate path untouched.
__global__ __launch_bounds__(256) void k_prep(const float* __restrict__ w,
                                              ushort* __restrict__ wt,
                                              const float* __restrict__ x,
                                              const float* __restrict__ gw,
                                              const float* __restrict__ gb,
                                              float* __restrict__ G,
                                              ushort* __restrict__ xb) {
    __shared__ __align__(16) char smem[64 * 65 * 4];
    const int bx = blockIdx.x;
    const int tid = threadIdx.x;
    if (bx < 2048) {
        // ---- Wt[f][e*512+d] = bf16(w[e][d][f]), 64x64 tile ----
        float (*tile)[65] = (float(*)[65])smem;   // tile[d][f]
        const int e = bx >> 6;
        const int f0 = ((bx >> 3) & 7) * 64;
        const int d0 = (bx & 7) * 64;
        const float* we = w + (size_t)e * DIM * DIM;

        // gather: thread (tq=f-quad 0..15, td=d 0..15), 4 rounds -> d0+td+16r
        const int tq = tid & 15, td = tid >> 4;
#pragma unroll
        for (int r = 0; r < 4; ++r) {
            const int d = td + 16 * r;
            const float4 v = *(const float4*)(we + (size_t)(d0 + d) * DIM + f0 + tq * 4);
            tile[d][tq * 4 + 0] = v.x;
            tile[d][tq * 4 + 1] = v.y;
            tile[d][tq * 4 + 2] = v.z;
            tile[d][tq * 4 + 3] = v.w;
        }
        __syncthreads();

        // scatter: thread (tx=d-chunk 0..7, ty=f 0..31; 2 f rows), 16B stores
        const int tx = tid & 7, ty = tid >> 3;
#pragma unroll
        for (int h = 0; h < 2; ++h) {
            const int f = ty + 32 * h;
            ushort8_tag: ;
            union { ushort u[8]; s16x8 v; } o;
#pragma unroll
            for (int j = 0; j < 8; ++j)
                o.u[j] = f2bf(tile[tx * 8 + j][f]);
            *(s16x8*)(wt + (size_t)(f0 + f) * KTOT + e * DIM + d0 + tx * 8) = o.v;
        }
    } else {
        // ---- gates (8 tokens/block, shfl softmax) + x -> bf16 ----
        float* xs = (float*)smem;
        const int t0 = (bx - 2048) * 8;
        const float* xBase = x + (size_t)t0 * DIM;
#pragma unroll
        for (int k = 0; k < 4; ++k) {
            int i4 = (k * 256 + tid) * 4;
            float4 v = *(const float4*)(xBase + i4);
            xs[i4 + 0] = v.x; xs[i4 + 1] = v.y; xs[i4 + 2] = v.z; xs[i4 + 3] = v.w;
            ushort4 o;
            o.x = f2bf(v.x); o.y = f2bf(v.y); o.z = f2bf(v.z); o.w = f2bf(v.w);
            *(ushort4*)(xb + (size_t)t0 * DIM + i4) = o;
        }
        __syncthreads();
        const int tok = tid >> 5;   // 0..7
        const int e = tid & 31;
        float l = gb[e];
        const float* xr = xs + tok * DIM;
#pragma unroll 8
        for (int d = 0; d < DIM; ++d)
            l += xr[d] * gw[d * NE + e];
        float mx = l;
#pragma unroll
        for (int m = 16; m >= 1; m >>= 1) mx = fmaxf(mx, __shfl_xor(mx, m));
        float ex = expf(l - mx);
        float s = ex;
#pragma unroll
        for (int m = 16; m >= 1; m >>= 1) s += __shfl_xor(s, m);
        G[(size_t)(t0 + tok) * NE + e] = ex / s;
    }
}

// ------------- main GEMM: kt-outer / e-inner, double-buffered LDS ----------
// R0 kernel verbatim (session-best: 148.5us, VGPR 60, 0 bank conflicts).
// 512 thr, 8 waves of 32x64, z=2 expert split, 2 blk/CU. A staged once per
// kt; B(e+1) DMA issued one-ahead so the barrier's vmcnt drain finds it
// complete. Fold per (kt,e) via transient pacc. LDS XOR-swizzle:
// LDS[row][c] = Glob[row][c ^ (row&7)].
__global__ __launch_bounds__(512, 2) void k_moe_gemm(const ushort* __restrict__ xb,
                                                     const ushort* __restrict__ wt,
                                                     const float* __restrict__ G,
                                                     float* __restrict__ out0,
                                                     float* __restrict__ out1) {
    __shared__ __align__(16) ushort As[2][BM * BK];   // 2 x 16 KB
    __shared__ __align__(16) ushort Bs[2][BN * BK];   // 2 x 16 KB
    __shared__ float Gs[16][BM];                      // 8 KB

    const int tid = threadIdx.x;
    const int m0 = blockIdx.y * BM;
    const int n0 = blockIdx.x * BN;
    const int e0 = blockIdx.z * 16;
    float* __restrict__ dst = blockIdx.z ? out1 : out0;

    for (int i = tid; i < 16 * BM; i += 512) {
        int e = i >> 7, r = i & 127;
        Gs[e][r] = G[(size_t)(m0 + r) * NE + e0 + e];
    }

    const int lane = tid & 63;
    const int wave = tid >> 6;            // 0..7
    const int wm = (wave & 3) * 32;       // 4 m-positions
    const int wn = (wave >> 2) * 64;      // 2 n-positions
    const int l15 = lane & 15;
    const int q = lane >> 4;              // 0..3
    const int keyR = l15 & 7;

    // reader byte offsets: row*128 + ((ks*4+q)^keyR)*16
    const int swz0 = ((q) ^ keyR) * 16;
    const int swz1 = ((4 + q) ^ keyR) * 16;
    const int rowA0 = (wm + l15) * 128;
    const int rowA1 = (wm + 16 + l15) * 128;
    const int rowB0 = (wn + l15) * 128;
    const int rowB1 = (wn + 16 + l15) * 128;
    const int rowB2 = (wn + 32 + l15) * 128;
    const int rowB3 = (wn + 48 + l15) * 128;

    // staging map: 512 thr x 16B = 8KB/round, 2 rounds per 16KB tile
    const int srow = tid >> 3;                       // 0..63 (row&7 == srow&7)
    const int chunk = tid & 7;
    const int scol = ((chunk ^ (srow & 7)) * 8);     // swizzled global column
    const ushort* aBase = xb + (size_t)(m0 + srow) * DIM + scol;
    const ushort* bBase = wt + (size_t)(n0 + srow) * KTOT + (size_t)e0 * DIM + scol;
    const int ldsOff = tid * 16;

    const f32x4 zv = {0.f, 0.f, 0.f, 0.f};
    f32x4 acc[2][4];
#pragma unroll
    for (int i = 0; i < 2; ++i)
#pragma unroll
        for (int j = 0; j < 4; ++j) acc[i][j] = zv;

    // prologue: stage A(kt=0) -> As[0], B(e=0,kt=0) -> Bs[0]
    gl_lds16(aBase, (char*)As[0] + ldsOff);
    gl_lds16(aBase + (size_t)64 * DIM, (char*)As[0] + 8192 + ldsOff);
    gl_lds16(bBase, (char*)Bs[0] + ldsOff);
    gl_lds16(bBase + (size_t)64 * KTOT, (char*)Bs[0] + 8192 + ldsOff);
    __syncthreads();

#pragma unroll 1
    for (int kt = 0; kt < 8; ++kt) {
        const char* Ab = (const char*)As[kt & 1];
#pragma unroll 1
        for (int ee = 0; ee < 16; ++ee) {
            // issue next-tile DMA (one ahead); barrier at end publishes it
            const int gn = kt * 16 + ee + 1;
            if (gn < 128) {
                const ushort* bN = bBase + (size_t)(gn & 15) * DIM + (gn >> 4) * BK;
                char* bL = (char*)Bs[gn & 1] + ldsOff;
                gl_lds16(bN, bL);
                gl_lds16(bN + (size_t)64 * KTOT, bL + 8192);
                if (ee == 15) {
                    const ushort* aN = aBase + (kt + 1) * BK;
                    char* aL = (char*)As[(kt + 1) & 1] + ldsOff;
                    gl_lds16(aN, aL);
                    gl_lds16(aN + (size_t)64 * DIM, aL + 8192);
                }
            }

            const char* Bb = (const char*)Bs[ee & 1];
            f32x4 pacc[2][4];
#pragma unroll
            for (int ks = 0; ks < 2; ++ks) {
                const int swz = ks ? swz1 : swz0;
                s16x8 a0 = *(const s16x8*)(Ab + rowA0 + swz);
                s16x8 a1 = *(const s16x8*)(Ab + rowA1 + swz);
                s16x8 b0 = *(const s16x8*)(Bb + rowB0 + swz);
                s16x8 b1 = *(const s16x8*)(Bb + rowB1 + swz);
                s16x8 b2 = *(const s16x8*)(Bb + rowB2 + swz);
                s16x8 b3 = *(const s16x8*)(Bb + rowB3 + swz);
                if (ks == 0) {
                    pacc[0][0] = __builtin_amdgcn_mfma_f32_16x16x32_bf16(a0, b0, zv, 0, 0, 0);
                    pacc[0][1] = __builtin_amdgcn_mfma_f32_16x16x32_bf16(a0, b1, zv, 0, 0, 0);
                    pacc[0][2] = __builtin_amdgcn_mfma_f32_16x16x32_bf16(a0, b2, zv, 0, 0, 0);
                    pacc[0][3] = __builtin_amdgcn_mfma_f32_16x16x32_bf16(a0, b3, zv, 0, 0, 0);
                    pacc[1][0] = __builtin_amdgcn_mfma_f32_16x16x32_bf16(a1, b0, zv, 0, 0, 0);
                    pacc[1][1] = __builtin_amdgcn_mfma_f32_16x16x32_bf16(a1, b1, zv, 0, 0, 0);
                    pacc[1][2] = __builtin_amdgcn_mfma_f32_16x16x32_bf16(a1, b2, zv, 0, 0, 0);
                    pacc[1][3] = __builtin_amdgcn_mfma_f32_16x16x32_bf16(a1, b3, zv, 0, 0, 0);
                } else {
                    pacc[0][0] = __builtin_amdgcn_mfma_f32_16x16x32_bf16(a0, b0, pacc[0][0], 0, 0, 0);
                    pacc[0][1] = __builtin_amdgcn_mfma_f32_16x16x32_bf16(a0, b1, pacc[0][1], 0, 0, 0);
                    pacc[0][2] = __builtin_amdgcn_mfma_f32_16x16x32_bf16(a0, b2, pacc[0][2], 0, 0, 0);
                    pacc[0][3] = __builtin_amdgcn_mfma_f32_16x16x32_bf16(a0, b3, pacc[0][3], 0, 0, 0);
                    pacc[1][0] = __builtin_amdgcn_mfma_f32_16x16x32_bf16(a1, b0, pacc[1][0], 0, 0, 0);
                    pacc[1][1] = __builtin_amdgcn_mfma_f32_16x16x32_bf16(a1, b1, pacc[1][1], 0, 0, 0);
                    pacc[1][2] = __builtin_amdgcn_mfma_f32_16x16x32_bf16(a1, b2, pacc[1][2], 0, 0, 0);
                    pacc[1][3] = __builtin_amdgcn_mfma_f32_16x16x32_bf16(a1, b3, pacc[1][3], 0, 0, 0);
                }
            }

            // fold with per-token gates (broadcast b128 reads from Gs)
#pragma unroll
            for (int i = 0; i < 2; ++i) {
                const f32x4 gt = *(const f32x4*)&Gs[ee][wm + i * 16 + q * 4];
#pragma unroll
                for (int j = 0; j < 4; ++j) {
                    acc[i][j][0] += gt[0] * pacc[i][j][0];
                    acc[i][j][1] += gt[1] * pacc[i][j][1];
                    acc[i][j][2] += gt[2] * pacc[i][j][2];
                    acc[i][j][3] += gt[3] * pacc[i][j][3];
                }
            }
            __syncthreads();   // publishes next buffers; DMA already complete
        }
    }

    // epilogue: plain stores (each element of dst owned by exactly one lane)
#pragma unroll
    for (int i = 0; i < 2; ++i) {
        const int tl = m0 + wm + i * 16 + q * 4;
#pragma unroll
        for (int j = 0; j < 4; ++j) {
            const int f = n0 + wn + j * 16 + l15;
            float* p = dst + (size_t)tl * DIM + f;
            p[0 * DIM] = acc[i][j][0];
            p[1 * DIM] = acc[i][j][1];
            p[2 * DIM] = acc[i][j][2];
            p[3 * DIM] = acc[i][j][3];
        }
    }
}

// ---- deterministic two-phase sum: out += P (both fully written upstream) ----
__global__ __launch_bounds__(256) void k_reduce(float* __restrict__ out,
                                                const float* __restrict__ P) {
    int i = (blockIdx.x * 256 + threadIdx.x) * 4;
    float4 a = *(const float4*)(out + i);
    float4 b = *(const float4*)(P + i);
    a.x += b.x; a.y += b.y; a.z += b.z; a.w += b.w;
    *(float4*)(out + i) = a;
}

extern "C" void kernel_launch(void* const* d_in, const int* in_sizes, int n_in,
                              void* d_out, int out_size, void* d_ws, size_t ws_size,
                              hipStream_t stream) {
    const float* x  = (const float*)d_in[0];   // [8192][512]
    const float* gw = (const float*)d_in[1];   // [512][32]
    const float* gb = (const float*)d_in[2];   // [32]
    const float* w  = (const float*)d_in[3];   // [32][512][512]
    float* out = (float*)d_out;                // [8192][512] fp32

    char* ws = (char*)d_ws;
    ushort* xb = (ushort*)ws;                            //  0..8 MiB
    ushort* wt = (ushort*)(ws + (8u << 20));             //  8..24 MiB
    float*  G  = (float*)(ws + (24u << 20));             // 24..25 MiB
    float*  P  = (float*)(ws + (25u << 20));             // 25..41 MiB

    k_prep<<<dim3(2048 + TOK / 8), dim3(256), 0, stream>>>(w, wt, x, gw, gb, G, xb);
    k_moe_gemm<<<dim3(DIM / BN, TOK / BM, 2), dim3(512), 0, stream>>>(xb, wt, G, out, P);
    k_reduce<<<dim3(TOK * DIM / 1024), dim3(256), 0, stream>>>(out, P);
}